// Round 7
// baseline (382.937 us; speedup 1.0000x reference)
//
#include <hip/hip_runtime.h>
#include <hip/hip_bf16.h>

// PIPNet interface scorer: out[p] = W2 . relu(W1 . concat(g1[il[p]], g2[ir[p]]) + b1) + b2
// R7: R2/R4/R6 proved the gather is pinned at a ~3.3 TB/s (26 G-lines/s) random
// service ceiling regardless of concurrency structure, with the 264MB f32 set
// thrashing the 256MB L3 (FETCH ~= full unique set per dispatch). Fix the DEMAND:
// pre-convert g1/g2 to bf16 (streaming, ws-resident). Random rows 256B->128B
// (1 line), dataset 128MB -> L3-resident. Main kernel = R2's proven structure
// with bf16 row gather. Fallback to f32 path if ws too small.

typedef __bf16 bf16x8 __attribute__((ext_vector_type(8)));
typedef float f32x16 __attribute__((ext_vector_type(16)));

__device__ __forceinline__ unsigned f2bf(float f) {
  union { float f; unsigned u; } v;
  v.f = f;
  unsigned u = v.u;
  return (u + 0x7fffu + ((u >> 16) & 1u)) >> 16;  // RNE
}

// Pre-kernel: W1 [128x128] f32 -> bf16 B-fragments for v_mfma_f32_32x32x16_bf16.
// Fragment (ks, nt, lane): n=lane&31, h=lane>>5; elems = W1[nt*32+n][ks*16+h*8+j]
__global__ __launch_bounds__(256) void w1_frag_kernel(
    const float* __restrict__ W1, uint4* __restrict__ w1f) {
  int t = blockIdx.x * 256 + threadIdx.x;  // 0..2047
  int lane = t & 63;
  int nt = (t >> 6) & 3;
  int ks = t >> 8;
  int n = lane & 31, h = lane >> 5;
  const float4* src =
      (const float4*)(W1 + ((nt * 32 + n) * 128 + ks * 16 + h * 8));
  float4 a = src[0], b = src[1];
  uint4 o;
  o.x = f2bf(a.x) | (f2bf(a.y) << 16);
  o.y = f2bf(a.z) | (f2bf(a.w) << 16);
  o.z = f2bf(b.x) | (f2bf(b.y) << 16);
  o.w = f2bf(b.z) | (f2bf(b.w) << 16);
  w1f[t] = o;
}

// Streaming f32 -> bf16 conversion of both feature arrays into ws.
__global__ __launch_bounds__(256) void cvt_bf16_kernel(
    const float4* __restrict__ a, const float4* __restrict__ b,
    uint2* __restrict__ da, uint2* __restrict__ db, int n4) {
  const int stride = gridDim.x * 256;
  for (int i = blockIdx.x * 256 + threadIdx.x; i < 2 * n4; i += stride) {
    const float4* s;
    uint2* d;
    int k;
    if (i < n4) { s = a; d = da; k = i; }
    else        { s = b; d = db; k = i - n4; }
    float4 v = s[k];
    d[k] = make_uint2(f2bf(v.x) | (f2bf(v.y) << 16),
                      f2bf(v.z) | (f2bf(v.w) << 16));
  }
}

#define LDS_STRIDE 136  // shorts; 272B rows, 16B-aligned, zero bank conflicts

// ---- Main kernel, bf16-row gather (128B per row = 1 cache line) ----
__global__ __launch_bounds__(256, 4) void pip_main_bf16(
    const uint4* __restrict__ gl, const uint4* __restrict__ gr,
    const int* __restrict__ il, const int* __restrict__ ir,
    const bf16x8* __restrict__ w1f,
    const float* __restrict__ b1, const float* __restrict__ w2,
    const float* __restrict__ b2,
    float* __restrict__ out, int P) {
  __shared__ unsigned short A[128 * LDS_STRIDE];  // 34,816 B -> 4 blocks/CU

  const int t = threadIdx.x;
  const int lane = t & 63;
  const int w = t >> 6;
  const int pair0 = blockIdx.x * 128;

  // Gather: 8 lanes per 128B bf16 row; wave does 8 rows/round, 8 rounds.
  const int sub = lane & 7;       // 16B slice within row
  const int grp = lane >> 3;      // 0..7
  const int side = grp & 1;       // fixed per thread
  const int pOff = grp >> 1;      // 0..3
  const uint4* feat = side ? gr : gl;
  const int* idxarr = side ? ir : il;

  int idxv[8];
#pragma unroll
  for (int j = 0; j < 8; ++j) {
    int gp = pair0 + j * 16 + w * 4 + pOff;
    int pidx = (gp < P) ? gp : (P - 1);
    idxv[j] = idxarr[pidx];
  }
  asm volatile("" : "+v"(idxv[0]), "+v"(idxv[1]), "+v"(idxv[2]), "+v"(idxv[3]),
                    "+v"(idxv[4]), "+v"(idxv[5]), "+v"(idxv[6]), "+v"(idxv[7]));

  uint4 v[8];
#pragma unroll
  for (int j = 0; j < 8; ++j)
    v[j] = feat[(size_t)idxv[j] * 8 + sub];
  asm volatile("" :
      "+v"(v[0].x), "+v"(v[0].y), "+v"(v[0].z), "+v"(v[0].w),
      "+v"(v[1].x), "+v"(v[1].y), "+v"(v[1].z), "+v"(v[1].w),
      "+v"(v[2].x), "+v"(v[2].y), "+v"(v[2].z), "+v"(v[2].w),
      "+v"(v[3].x), "+v"(v[3].y), "+v"(v[3].z), "+v"(v[3].w),
      "+v"(v[4].x), "+v"(v[4].y), "+v"(v[4].z), "+v"(v[4].w),
      "+v"(v[5].x), "+v"(v[5].y), "+v"(v[5].z), "+v"(v[5].w),
      "+v"(v[6].x), "+v"(v[6].y), "+v"(v[6].z), "+v"(v[6].w),
      "+v"(v[7].x), "+v"(v[7].y), "+v"(v[7].z), "+v"(v[7].w));
#pragma unroll
  for (int j = 0; j < 8; ++j) {
    int pair = j * 16 + w * 4 + pOff;
    *(uint4*)(A + pair * LDS_STRIDE + side * 64 + sub * 8) = v[j];
  }
  __syncthreads();

  // ---- Compute: wave w handles pairs [w*32, w*32+32), n = 0..127 ----
  const int n = lane & 31;
  const int h = lane >> 5;

  f32x16 acc[4];
#pragma unroll
  for (int nt = 0; nt < 4; ++nt)
#pragma unroll
    for (int i = 0; i < 16; ++i) acc[nt][i] = 0.0f;

  const unsigned short* Arow = A + (w * 32 + n) * LDS_STRIDE + h * 8;
#pragma unroll
  for (int ks = 0; ks < 8; ++ks) {
    bf16x8 af = *(const bf16x8*)(Arow + ks * 16);
#pragma unroll
    for (int nt = 0; nt < 4; ++nt) {
      bf16x8 bfr = w1f[(ks * 4 + nt) * 64 + lane];
      acc[nt] = __builtin_amdgcn_mfma_f32_32x32x16_bf16(af, bfr, acc[nt], 0, 0, 0);
    }
  }

  // ---- Epilogue: out[p] = sum_n relu(acc + b1[n]) * w2[n] + b2 ----
  // C/D layout: col(n) = lane&31 (+32*nt), row(m) = (r&3) + 8*(r>>2) + 4*h.
  float b1v[4], w2v[4];
#pragma unroll
  for (int nt = 0; nt < 4; ++nt) {
    b1v[nt] = b1[nt * 32 + n];
    w2v[nt] = w2[nt * 32 + n];
  }
  const float bias2 = b2[0];

#pragma unroll
  for (int r = 0; r < 16; ++r) {
    float s = 0.0f;
#pragma unroll
    for (int nt = 0; nt < 4; ++nt) {
      float vv = acc[nt][r] + b1v[nt];
      vv = fmaxf(vv, 0.0f);
      s = fmaf(vv, w2v[nt], s);
    }
    s += __shfl_xor(s, 1);
    s += __shfl_xor(s, 2);
    s += __shfl_xor(s, 4);
    s += __shfl_xor(s, 8);
    s += __shfl_xor(s, 16);
    if (n == 0) {
      int row = (r & 3) + 8 * (r >> 2) + 4 * h;
      int gp = pair0 + w * 32 + row;
      if (gp < P) out[gp] = s + bias2;
    }
  }
}

// ---- Fallback main kernel (R2-proven): direct f32 gather ----
__global__ __launch_bounds__(256, 3) void pip_main_f32(
    const float* __restrict__ g1, const float* __restrict__ g2,
    const int* __restrict__ il, const int* __restrict__ ir,
    const bf16x8* __restrict__ w1f,
    const float* __restrict__ b1, const float* __restrict__ w2,
    const float* __restrict__ b2,
    float* __restrict__ out, int P) {
  __shared__ unsigned short A[128 * LDS_STRIDE];

  const int t = threadIdx.x;
  const int lane = t & 63;
  const int w = t >> 6;
  const int pair0 = blockIdx.x * 128;

  const int sub = lane & 15;
  const int g = lane >> 4;
  const int side = g & 1;
  const int pairB = w * 2 + (g >> 1);
  const float* feat = side ? g2 : g1;
  const int* idxarr = side ? ir : il;

  int idxv[16];
#pragma unroll
  for (int j = 0; j < 16; ++j) {
    int gp = pair0 + j * 8 + pairB;
    int pidx = (gp < P) ? gp : (P - 1);
    idxv[j] = idxarr[pidx];
  }
#pragma unroll
  for (int j = 0; j < 16; ++j) {
    float4 v = *(const float4*)(feat + (size_t)idxv[j] * 64 + sub * 4);
    unsigned lo = f2bf(v.x) | (f2bf(v.y) << 16);
    unsigned hi = f2bf(v.z) | (f2bf(v.w) << 16);
    *(uint2*)(A + (j * 8 + pairB) * LDS_STRIDE + side * 64 + sub * 4) =
        make_uint2(lo, hi);
  }
  __syncthreads();

  const int n = lane & 31;
  const int h = lane >> 5;

  f32x16 acc[4];
#pragma unroll
  for (int nt = 0; nt < 4; ++nt)
#pragma unroll
    for (int i = 0; i < 16; ++i) acc[nt][i] = 0.0f;

  const unsigned short* Arow = A + (w * 32 + n) * LDS_STRIDE + h * 8;
#pragma unroll
  for (int ks = 0; ks < 8; ++ks) {
    bf16x8 af = *(const bf16x8*)(Arow + ks * 16);
#pragma unroll
    for (int nt = 0; nt < 4; ++nt) {
      bf16x8 bfr = w1f[(ks * 4 + nt) * 64 + lane];
      acc[nt] = __builtin_amdgcn_mfma_f32_32x32x16_bf16(af, bfr, acc[nt], 0, 0, 0);
    }
  }

  float b1v[4], w2v[4];
#pragma unroll
  for (int nt = 0; nt < 4; ++nt) {
    b1v[nt] = b1[nt * 32 + n];
    w2v[nt] = w2[nt * 32 + n];
  }
  const float bias2 = b2[0];

#pragma unroll
  for (int r = 0; r < 16; ++r) {
    float s = 0.0f;
#pragma unroll
    for (int nt = 0; nt < 4; ++nt) {
      float vv = acc[nt][r] + b1v[nt];
      vv = fmaxf(vv, 0.0f);
      s = fmaf(vv, w2v[nt], s);
    }
    s += __shfl_xor(s, 1);
    s += __shfl_xor(s, 2);
    s += __shfl_xor(s, 4);
    s += __shfl_xor(s, 8);
    s += __shfl_xor(s, 16);
    if (n == 0) {
      int row = (r & 3) + 8 * (r >> 2) + 4 * h;
      int gp = pair0 + w * 32 + row;
      if (gp < P) out[gp] = s + bias2;
    }
  }
}

extern "C" void kernel_launch(void* const* d_in, const int* in_sizes, int n_in,
                              void* d_out, int out_size, void* d_ws, size_t ws_size,
                              hipStream_t stream) {
  const float* g1 = (const float*)d_in[0];   // graph1_x [N,64] f32
  const float* g2 = (const float*)d_in[1];   // graph2_x [N,64] f32
  const int* il = (const int*)d_in[2];       // idx_left [P] int32
  const int* ir = (const int*)d_in[3];       // idx_right [P] int32
  const float* W1 = (const float*)d_in[4];   // [128,128]
  const float* b1 = (const float*)d_in[5];   // [128]
  const float* w2 = (const float*)d_in[6];   // [1,128]
  const float* b2 = (const float*)d_in[7];   // [1]
  float* out = (float*)d_out;                // [P,1] f32
  const int P = out_size;

  // ws layout: [0,32K) W1 bf16 fragments; [32K, +sz) g1 bf16; [.., +sz) g2 bf16
  w1_frag_kernel<<<8, 256, 0, stream>>>(W1, (uint4*)d_ws);

  const size_t sz1 = (size_t)in_sizes[0] * 2;  // bf16 bytes per feature array
  const size_t need = 32768 + sz1 + (size_t)in_sizes[1] * 2;
  const int nblocks = (P + 127) / 128;

  if (ws_size >= need) {
    char* wsc = (char*)d_ws;
    uint2* gl = (uint2*)(wsc + 32768);
    uint2* gr = (uint2*)(wsc + 32768 + sz1);
    const int n4 = in_sizes[0] / 4;  // float4 count per array (8M)
    cvt_bf16_kernel<<<8192, 256, 0, stream>>>(
        (const float4*)g1, (const float4*)g2, gl, gr, n4);
    pip_main_bf16<<<nblocks, 256, 0, stream>>>(
        (const uint4*)gl, (const uint4*)gr, il, ir, (const bf16x8*)d_ws,
        b1, w2, b2, out, P);
  } else {
    pip_main_f32<<<nblocks, 256, 0, stream>>>(
        g1, g2, il, ir, (const bf16x8*)d_ws, b1, w2, b2, out, P);
  }
}